// Round 3
// baseline (55687.567 us; speedup 1.0000x reference)
//
#include <hip/hip_runtime.h>

#define Bn 4096
#define Tn 256
#define NZ 64
#define Hn 512
#define G4n 2048
#define INn 68
#define DPRv 24.0f
#define MB 32
#define NWAVE 8
#define NTHREADS 512
#define NBLK (Bn / MB) /* 128 */

// packed stream geometry (unsigned short units)
#define PK_WSTRIDE (32 * 10 * 64 * 8) /* 163840 per wave */
#define PK_KSTRIDE (10 * 64 * 8)      /* 5120 per kk */
#define PK_FSTRIDE (64 * 8)           /* 512 per fragment */
#define EP_WSTRIDE (5 * 8 * 64 * 8)   /* 20480 per wave */
#define EP_KSTRIDE (8 * 64 * 8)       /* 4096 per kk */

typedef short short8 __attribute__((ext_vector_type(8)));
typedef float floatx16 __attribute__((ext_vector_type(16)));

__device__ __forceinline__ unsigned short f2bf(float f) {
  unsigned int u = __float_as_uint(f);
  u += 0x7FFFu + ((u >> 16) & 1u);
  return (unsigned short)(u >> 16);
}
__device__ __forceinline__ float fsig(float x) {
  return __builtin_amdgcn_rcpf(1.0f + __builtin_amdgcn_exp2f(x * -1.4426950408889634f));
}
__device__ __forceinline__ float ftanh(float x) {
  return 1.0f - 2.0f * __builtin_amdgcn_rcpf(1.0f + __builtin_amdgcn_exp2f(x * 2.8853900817779268f));
}

// Pack weights (bf16) in the exact per-(wave,kk,fragment,lane) consumption order.
// Also zeroes the rendezvous counter (graph replay re-runs this each launch).
__global__ void prep_pack(const float* __restrict__ Wih, const float* __restrict__ Whh,
                          const float* __restrict__ W1u,
                          unsigned short* __restrict__ pk, unsigned short* __restrict__ epk,
                          unsigned int* __restrict__ cnt) {
  const int idx = blockIdx.x * blockDim.x + threadIdx.x;
  if (idx == 0) *cnt = 0u;
  if (idx < 163840) {
    const int lane = idx & 63;
    const int fragid = idx >> 6;
    const int f = fragid % 10;
    const int kk = (fragid / 10) % 32;
    const int w = fragid / 320;
    const int l31 = lane & 31, half = lane >> 5;
    const int k0 = kk * 16 + half * 8;
    unsigned short* dst = pk + (size_t)idx * 8;
    if (f < 2) {
      const int n = w * 64 + f * 32 + l31;
#pragma unroll
      for (int j = 0; j < 8; ++j) dst[j] = f2bf(W1u[n * Hn + k0 + j]);
    } else {
      const int g = (f - 2) >> 1, s = (f - 2) & 1;
      const int n = g * Hn + w * 64 + s * 32 + l31;
#pragma unroll
      for (int j = 0; j < 8; ++j) dst[j] = f2bf(Whh[n * Hn + k0 + j]);
    }
  }
  const int e = idx - 163840;
  if (e >= 0 && e < 20480) {
    const int lane = e & 63;
    const int fragid = e >> 6;
    const int fs = fragid % 8;
    const int kk = (fragid / 8) % 5;
    const int w = fragid / 40;
    const int g = fs >> 1, s = fs & 1;
    const int l31 = lane & 31, half = lane >> 5;
    const int n = g * Hn + w * 64 + s * 32 + l31;
    unsigned short* dst = epk + (size_t)e * 8;
#pragma unroll
    for (int j = 0; j < 8; ++j) {
      const int c = kk * 16 + half * 8 + j;
      float v = 0.0f;
      if (c < 64) v = Wih[n * INn + 3 + c];
      else if (c == 64) v = Wih[n * INn + 0];
      else if (c == 65) v = Wih[n * INn + 1];
      else if (c == 67) v = Wih[n * INn + 67];
      dst[j] = f2bf(v);
    }
  }
}

// Persistent recurrent kernel: each block owns 32 batch rows for all 256 steps.
// A per-step global rendezvous keeps all blocks in the same step window so the
// shared 2.8MB weight stream stays L2-resident (convoy effect). The rendezvous
// carries NO data dependency — it is purely a pacing mechanism.
__launch_bounds__(NTHREADS, 2)
__global__ void lstm_seq(const float* __restrict__ noise, const float* __restrict__ cluster,
                         const float* __restrict__ gap, const float* __restrict__ Wih,
                         const float* __restrict__ bih, const float* __restrict__ bhh,
                         const float* __restrict__ b1p, const float* __restrict__ W2p,
                         const float* __restrict__ b2p,
                         const unsigned short* __restrict__ pk,
                         const unsigned short* __restrict__ epk,
                         unsigned int* __restrict__ cnt,
                         float* __restrict__ out) {
  // h in bf16 A-fragment layout, XOR-swizzled: byte(r,col) = r*1024 + ((col*2) ^ (r<<4))
  __shared__ __align__(16) unsigned short hA[MB * Hn];      // 32 KB
  // extras tile [32 rows][128 cols padded], swizzle: byte = r*256 + ((col*2) ^ ((r&15)<<4))
  __shared__ __align__(16) unsigned short extA[MB * 128];   // 8 KB
  __shared__ float partial[NWAVE][MB];
  __shared__ float dp_lds[MB];

  const int tid = threadIdx.x;
  const int w = tid >> 6;
  const int lane = tid & 63;
  const int l31 = lane & 31;
  const int half = lane >> 5;
  const int r0 = blockIdx.x * MB;
  const int cb = w * 64;           // this wave's hidden-column base
  const int c0 = cb + l31;         // sub-tile 0 column
  const int c1 = cb + 32 + l31;    // sub-tile 1 column

  // ---- zero LDS (h0 = 0; ext padding = 0) ----
  short8 zero8 = {0, 0, 0, 0, 0, 0, 0, 0};
  for (int i = tid; i < MB * Hn / 8; i += NTHREADS) ((short8*)hA)[i] = zero8;
  for (int i = tid; i < MB * 128 / 8; i += NTHREADS) ((short8*)extA)[i] = zero8;

  // ---- loop-invariant preloads ----
  float biasv[4][2], wih2[4][2];
#pragma unroll
  for (int g = 0; g < 4; ++g)
#pragma unroll
    for (int s = 0; s < 2; ++s) {
      int n = g * Hn + cb + s * 32 + l31;
      biasv[g][s] = bih[n] + bhh[n];
      wih2[g][s] = Wih[n * INn + 2];   // dp column of W_ih (exact f32 path)
    }
  const float b1v0 = b1p[c0], b1v1 = b1p[c1];
  const float w2v0 = W2p[c0], w2v1 = W2p[c1];
  const float b2v = b2p[0];
  const float clusf = cluster[r0 + (tid & 31)];

  const unsigned short* const ps = pk + (size_t)w * PK_WSTRIDE + (size_t)lane * 8;
  const unsigned short* const es = epk + (size_t)w * EP_WSTRIDE + (size_t)lane * 8;

  // ---- stage extras for t = 0 ----
  {
    const int row = tid >> 4, kq = (tid & 15) << 2;
    const float4 v = *(const float4*)(noise + ((size_t)(r0 + row) * Tn + 0) * NZ + kq);
    ushort4 hb;
    hb.x = f2bf(v.x); hb.y = f2bf(v.y); hb.z = f2bf(v.z); hb.w = f2bf(v.w);
    *(ushort4*)((char*)extA + row * 256 + ((kq << 1) ^ ((row & 15) << 4))) = hb;
    if (tid < MB) {
      const size_t gb = ((size_t)(r0 + tid) * (Tn + 1) + 0) * 2;
      ushort4 hg;
      hg.x = f2bf(gap[gb]); hg.y = f2bf(gap[gb + 1]); hg.z = 0; hg.w = f2bf(clusf);
      *(ushort4*)((char*)extA + tid * 256 + (128 ^ ((tid & 15) << 4))) = hg;
    }
  }

  float c_reg0[16], c_reg1[16];
#pragma unroll
  for (int q = 0; q < 16; ++q) { c_reg0[q] = 0.f; c_reg1[q] = 0.f; }

  __syncthreads();

  for (int t = 0; t <= Tn; ++t) {
    // ========== fused Z + G phase: one sequential 320KB weight stream per wave ==========
    floatx16 zacc[2];
    floatx16 acc[4][2];
#pragma unroll
    for (int s = 0; s < 2; ++s)
#pragma unroll
      for (int q = 0; q < 16; ++q) zacc[s][q] = 0.f;
#pragma unroll
    for (int g = 0; g < 4; ++g)
#pragma unroll
      for (int s = 0; s < 2; ++s)
#pragma unroll
        for (int q = 0; q < 16; ++q) acc[g][s][q] = 0.f;

    for (int kk = 0; kk < 32; ++kk) {
      const int k0 = (kk << 4) + (half << 3);
      const short8 a = *(const short8*)((const char*)hA + (l31 << 10) + ((k0 << 1) ^ (l31 << 4)));
      const unsigned short* pb = ps + kk * PK_KSTRIDE;
      zacc[0] = __builtin_amdgcn_mfma_f32_32x32x16_bf16(a, *(const short8*)(pb), zacc[0], 0, 0, 0);
      zacc[1] = __builtin_amdgcn_mfma_f32_32x32x16_bf16(a, *(const short8*)(pb + PK_FSTRIDE), zacc[1], 0, 0, 0);
#pragma unroll
      for (int g = 0; g < 4; ++g)
#pragma unroll
        for (int s = 0; s < 2; ++s)
          acc[g][s] = __builtin_amdgcn_mfma_f32_32x32x16_bf16(
              a, *(const short8*)(pb + (2 + g * 2 + s) * PK_FSTRIDE), acc[g][s], 0, 0, 0);
    }
#pragma unroll
    for (int kk = 0; kk < 5; ++kk) {
      const int k0 = (kk << 4) + (half << 3);
      const short8 a = *(const short8*)((const char*)extA + (l31 << 8) + ((k0 << 1) ^ ((l31 & 15) << 4)));
      const unsigned short* eb = es + kk * EP_KSTRIDE;
#pragma unroll
      for (int g = 0; g < 4; ++g)
#pragma unroll
        for (int s = 0; s < 2; ++s)
          acc[g][s] = __builtin_amdgcn_mfma_f32_32x32x16_bf16(
              a, *(const short8*)(eb + (g * 2 + s) * PK_FSTRIDE), acc[g][s], 0, 0, 0);
    }

    // z finish + dp partials
    {
      float part[16];
#pragma unroll
      for (int q = 0; q < 16; ++q) {
        const float z0 = ftanh(zacc[0][q] + b1v0);
        const float z1 = ftanh(zacc[1][q] + b1v1);
        part[q] = z0 * w2v0 + z1 * w2v1;
      }
#pragma unroll
      for (int m = 1; m <= 16; m <<= 1)
#pragma unroll
        for (int q = 0; q < 16; ++q) part[q] += __shfl_xor(part[q], m, 64);
      if (l31 == 0) {
#pragma unroll
        for (int q = 0; q < 16; ++q)
          partial[w][(q & 3) + ((q >> 2) << 3) + (half << 2)] = part[q];
      }
    }

    __syncthreads();  // B1: partial complete; all reads of hA/extA complete

    // ================= dp + output + stage extras for t+1 =================
    if (tid < MB) {
      float ssum = b2v;
#pragma unroll
      for (int ww = 0; ww < NWAVE; ++ww) ssum += partial[ww][tid];
      const float dpv = DPRv * ftanh(ssum);
      dp_lds[tid] = dpv;
      const size_t gb = ((size_t)(r0 + tid) * (Tn + 1) + t) * 2;
      const float g0 = gap[gb], g1 = gap[gb + 1];
      float* op = out + ((size_t)(r0 + tid) * (Tn + 1) + t) * 3;
      op[0] = g0; op[1] = g1; op[2] = dpv;
    }
    if (t < Tn - 1) {
      const int row = tid >> 4, kq = (tid & 15) << 2;
      const float4 v = *(const float4*)(noise + ((size_t)(r0 + row) * Tn + (t + 1)) * NZ + kq);
      ushort4 hb;
      hb.x = f2bf(v.x); hb.y = f2bf(v.y); hb.z = f2bf(v.z); hb.w = f2bf(v.w);
      *(ushort4*)((char*)extA + row * 256 + ((kq << 1) ^ ((row & 15) << 4))) = hb;
      if (tid < MB) {
        const size_t gb = ((size_t)(r0 + tid) * (Tn + 1) + (t + 1)) * 2;
        ushort4 hg;
        hg.x = f2bf(gap[gb]); hg.y = f2bf(gap[gb + 1]); hg.z = 0; hg.w = f2bf(clusf);
        *(ushort4*)((char*)extA + tid * 256 + (128 ^ ((tid & 15) << 4))) = hg;
      }
    }
    __syncthreads();  // B2: dp_lds visible; hA safe to overwrite

    // ================= cell update, write h (bf16, swizzled) =================
    if (t < Tn) {
      float dpv[16];
#pragma unroll
      for (int q = 0; q < 16; ++q)
        dpv[q] = dp_lds[(q & 3) + ((q >> 2) << 3) + (half << 2)];
#pragma unroll
      for (int s = 0; s < 2; ++s) {
        const int colb = (cb + s * 32 + l31) << 1;
#pragma unroll
        for (int q = 0; q < 16; ++q) {
          const float gi = acc[0][s][q] + biasv[0][s] + dpv[q] * wih2[0][s];
          const float gf = acc[1][s][q] + biasv[1][s] + dpv[q] * wih2[1][s];
          const float gg = acc[2][s][q] + biasv[2][s] + dpv[q] * wih2[2][s];
          const float go = acc[3][s][q] + biasv[3][s] + dpv[q] * wih2[3][s];
          float cv = (s == 0) ? c_reg0[q] : c_reg1[q];
          cv = fsig(gf) * cv + fsig(gi) * ftanh(gg);
          const float hv = fsig(go) * ftanh(cv);
          if (s == 0) c_reg0[q] = cv; else c_reg1[q] = cv;
          const int r = (q & 3) + ((q >> 2) << 3) + (half << 2);
          *(unsigned short*)((char*)hA + (r << 10) + (colb ^ (r << 4))) = f2bf(hv);
        }
      }

      __syncthreads();  // B3: hA ready for next step

      // ---- global rendezvous: keep all blocks in the same step window ----
      if (tid == 0) {
        __hip_atomic_fetch_add(cnt, 1u, __ATOMIC_RELAXED, __HIP_MEMORY_SCOPE_AGENT);
        const unsigned int tgt = (unsigned int)NBLK * (unsigned int)(t + 1);
        while (__hip_atomic_load(cnt, __ATOMIC_RELAXED, __HIP_MEMORY_SCOPE_AGENT) < tgt)
          __builtin_amdgcn_s_sleep(2);
      }
      __syncthreads();  // B4: released together
    } else {
      __syncthreads();  // B3 (final step, no rendezvous needed)
    }
  }
}

extern "C" void kernel_launch(void* const* d_in, const int* in_sizes, int n_in,
                              void* d_out, int out_size, void* d_ws, size_t ws_size,
                              hipStream_t stream) {
  const float* noise   = (const float*)d_in[0];
  const float* cluster = (const float*)d_in[1];
  const float* gap     = (const float*)d_in[2];
  const float* Wih     = (const float*)d_in[3];
  const float* Whh     = (const float*)d_in[4];
  const float* bih     = (const float*)d_in[5];
  const float* bhh     = (const float*)d_in[6];
  const float* W1      = (const float*)d_in[7];
  const float* b1      = (const float*)d_in[8];
  const float* W2      = (const float*)d_in[9];
  const float* b2      = (const float*)d_in[10];

  unsigned short* pkw = (unsigned short*)d_ws;                    // 8*163840 shorts = 2.5 MB
  unsigned short* epk = pkw + (size_t)NWAVE * PK_WSTRIDE;         // 8*20480 shorts = 320 KB
  unsigned int* cnt = (unsigned int*)(epk + (size_t)NWAVE * EP_WSTRIDE);

  prep_pack<<<(184320 + 255) / 256, 256, 0, stream>>>(Wih, Whh, W1, pkw, epk, cnt);
  lstm_seq<<<NBLK, NTHREADS, 0, stream>>>(noise, cluster, gap, Wih, bih, bhh, b1, W2, b2,
                                          pkw, epk, cnt, (float*)d_out);
}

// Round 5
// 13545.546 us; speedup vs baseline: 4.1111x; 4.1111x over previous
//
#include <hip/hip_runtime.h>

#define Bn 4096
#define Tn 256
#define NZ 64
#define Hn 512
#define INn 68
#define DPRv 24.0f
#define MB 32
#define NWAVE 8
#define NTHREADS 512
#define NBLK 128

// unified per-wave weight stream: 37 groups (32 h + 5 ext) x 10 frags x 64 lanes x 8 shorts
#define NGRP 37
#define GRP_SHORTS (10 * 64 * 8)            /* 5120 */
#define WAVE_SHORTS (NGRP * GRP_SHORTS)     /* 189440 */
#define STREAM_SHORTS (NWAVE * WAVE_SHORTS) /* 1515520 */

typedef short short8 __attribute__((ext_vector_type(8)));
typedef float floatx16 __attribute__((ext_vector_type(16)));

__device__ __forceinline__ unsigned short f2bf(float f) {
  unsigned int u = __float_as_uint(f);
  u += 0x7FFFu + ((u >> 16) & 1u);
  return (unsigned short)(u >> 16);
}
__device__ __forceinline__ float fsig(float x) {
  return __builtin_amdgcn_rcpf(1.0f + __builtin_amdgcn_exp2f(x * -1.4426950408889634f));
}
__device__ __forceinline__ float ftanh(float x) {
  return 1.0f - 2.0f * __builtin_amdgcn_rcpf(1.0f + __builtin_amdgcn_exp2f(x * 2.8853900817779268f));
}

// Pack all weights (bf16) into the unified per-(wave,group,frag,lane) stream.
// Group gi<32: K-slice gi of h (H=512). frags 0,1 -> W1 (z); frags 2..9 -> W_hh (g,s).
// Group gi>=32: K-slice of the 80-wide ext input. frags 0,1 -> ZERO (zacc padding);
//   frags 2..9 -> W_ih rearranged cols [noise 0..63][gap0][gap1][dp=0][clus][pad..79].
__global__ void prep_pack(const float* __restrict__ Wih, const float* __restrict__ Whh,
                          const float* __restrict__ W1u, unsigned short* __restrict__ us) {
  const int idx = blockIdx.x * blockDim.x + threadIdx.x;
  if (idx >= STREAM_SHORTS / 8) return;
  const int lane = idx & 63;
  const int fragid = idx >> 6;
  const int f = fragid % 10;
  const int gi = (fragid / 10) % NGRP;
  const int w = fragid / (10 * NGRP);
  const int l31 = lane & 31, half = lane >> 5;
  unsigned short v8[8];
  if (gi < 32) {
    const int k0 = gi * 16 + half * 8;
    if (f < 2) {
      const int n = w * 64 + f * 32 + l31;
#pragma unroll
      for (int j = 0; j < 8; ++j) v8[j] = f2bf(W1u[n * Hn + k0 + j]);
    } else {
      const int g = (f - 2) >> 1, s = (f - 2) & 1;
      const int n = g * Hn + w * 64 + s * 32 + l31;
#pragma unroll
      for (int j = 0; j < 8; ++j) v8[j] = f2bf(Whh[n * Hn + k0 + j]);
    }
  } else {
    const int kk = gi - 32;
    const int cb = kk * 16 + half * 8;
    if (f < 2) {
#pragma unroll
      for (int j = 0; j < 8; ++j) v8[j] = 0;
    } else {
      const int g = (f - 2) >> 1, s = (f - 2) & 1;
      const int n = g * Hn + w * 64 + s * 32 + l31;
#pragma unroll
      for (int j = 0; j < 8; ++j) {
        const int c = cb + j;
        float v = 0.0f;
        if (c < 64) v = Wih[n * INn + 3 + c];
        else if (c == 64) v = Wih[n * INn + 0];
        else if (c == 65) v = Wih[n * INn + 1];
        else if (c == 67) v = Wih[n * INn + 67];
        v8[j] = f2bf(v);
      }
    }
  }
  unsigned short* dst = us + (size_t)idx * 8;
#pragma unroll
  for (int j = 0; j < 8; ++j) dst[j] = v8[j];
}

// Persistent recurrent kernel: each block owns 32 batch rows for all 256 steps.
// The weight loop is source-level double-buffered (load group i+1 into regs,
// then MFMA-consume group i) so ~10 1KB loads stay in flight per wave; the
// compiler's own waitcnt insertion produces the counted waits.
__launch_bounds__(NTHREADS, 2)
__global__ void lstm_seq(const float* __restrict__ noise, const float* __restrict__ cluster,
                         const float* __restrict__ gap, const float* __restrict__ Wih,
                         const float* __restrict__ bih, const float* __restrict__ bhh,
                         const float* __restrict__ b1p, const float* __restrict__ W2p,
                         const float* __restrict__ b2p,
                         const unsigned short* __restrict__ us,
                         float* __restrict__ out) {
  __shared__ __align__(16) unsigned short hA[MB * Hn];      // 32 KB, swizzled A-layout
  __shared__ __align__(16) unsigned short extA[MB * 128];   // 8 KB, swizzled
  __shared__ float partial[NWAVE][MB];
  __shared__ float dp_lds[MB];

  const int tid = threadIdx.x;
  const int w = tid >> 6;
  const int lane = tid & 63;
  const int l31 = lane & 31;
  const int half = lane >> 5;
  const int r0 = blockIdx.x * MB;
  const int cb = w * 64;
  const int c0 = cb + l31;
  const int c1 = cb + 32 + l31;

  short8 zero8 = {0, 0, 0, 0, 0, 0, 0, 0};
  for (int i = tid; i < MB * Hn / 8; i += NTHREADS) ((short8*)hA)[i] = zero8;
  for (int i = tid; i < MB * 128 / 8; i += NTHREADS) ((short8*)extA)[i] = zero8;

  float biasv[4][2], wih2[4][2];
#pragma unroll
  for (int g = 0; g < 4; ++g)
#pragma unroll
    for (int s = 0; s < 2; ++s) {
      int n = g * Hn + cb + s * 32 + l31;
      biasv[g][s] = bih[n] + bhh[n];
      wih2[g][s] = Wih[n * INn + 2];
    }
  const float b1v0 = b1p[c0], b1v1 = b1p[c1];
  const float w2v0 = W2p[c0], w2v1 = W2p[c1];
  const float b2v = b2p[0];
  const float clusf = cluster[r0 + (tid & 31)];

  // per-lane base of this wave's weight stream (short8 units)
  const short8* const ws = (const short8*)us + (size_t)w * (NGRP * 10 * 64) + lane;

  // stage extras for t = 0
  {
    const int row = tid >> 4, kq = (tid & 15) << 2;
    const float4 v = *(const float4*)(noise + ((size_t)(r0 + row) * Tn + 0) * NZ + kq);
    ushort4 hb;
    hb.x = f2bf(v.x); hb.y = f2bf(v.y); hb.z = f2bf(v.z); hb.w = f2bf(v.w);
    *(ushort4*)((char*)extA + row * 256 + ((kq << 1) ^ ((row & 15) << 4))) = hb;
    if (tid < MB) {
      const size_t gb = ((size_t)(r0 + tid) * (Tn + 1) + 0) * 2;
      ushort4 hg;
      hg.x = f2bf(gap[gb]); hg.y = f2bf(gap[gb + 1]); hg.z = 0; hg.w = f2bf(clusf);
      *(ushort4*)((char*)extA + tid * 256 + (128 ^ ((tid & 15) << 4))) = hg;
    }
  }

  float c_reg0[16], c_reg1[16];
#pragma unroll
  for (int q = 0; q < 16; ++q) { c_reg0[q] = 0.f; c_reg1[q] = 0.f; }

  __syncthreads();

  for (int t = 0; t <= Tn; ++t) {
    floatx16 zacc[2];
    floatx16 acc[4][2];
#pragma unroll
    for (int s = 0; s < 2; ++s)
#pragma unroll
      for (int q = 0; q < 16; ++q) zacc[s][q] = 0.f;
#pragma unroll
    for (int g = 0; g < 4; ++g)
#pragma unroll
      for (int s = 0; s < 2; ++s)
#pragma unroll
        for (int q = 0; q < 16; ++q) acc[g][s][q] = 0.f;

    // load all 10 fragments of group g into registers (plain C++ -> compiler
    // emits 10 independent global_load_dwordx4 with its own counted waits)
    auto ldgrp = [&](int g, short8(&b)[10]) {
      const short8* p = ws + g * (10 * 64);
#pragma unroll
      for (int f = 0; f < 10; ++f) b[f] = p[f * 64];
    };
    // branchless A-fragment fetch + 10 MFMAs for group g
    auto consume = [&](int g, const short8(&b)[10]) {
      const int isH = (g < 32) ? 1 : 0;
      const int gg = isH ? g : (g - 32);
      const int k0 = (gg << 4) + (half << 3);
      const int rsh = isH ? 10 : 8;
      const int msk = isH ? l31 : (l31 & 15);
      const char* base = isH ? (const char*)hA : (const char*)extA;
      const short8 a = *(const short8*)(base + (l31 << rsh) + ((k0 << 1) ^ (msk << 4)));
      zacc[0] = __builtin_amdgcn_mfma_f32_32x32x16_bf16(a, b[0], zacc[0], 0, 0, 0);
      zacc[1] = __builtin_amdgcn_mfma_f32_32x32x16_bf16(a, b[1], zacc[1], 0, 0, 0);
#pragma unroll
      for (int g2 = 0; g2 < 4; ++g2)
#pragma unroll
        for (int s = 0; s < 2; ++s)
          acc[g2][s] = __builtin_amdgcn_mfma_f32_32x32x16_bf16(a, b[2 + g2 * 2 + s], acc[g2][s], 0, 0, 0);
    };

    short8 bufA[10], bufB[10];
    ldgrp(0, bufA);
    for (int ii = 0; ii < 18; ++ii) {
      const int g0 = 2 * ii;
      ldgrp(g0 + 1, bufB);
      consume(g0, bufA);
      ldgrp(g0 + 2, bufA);   // g0+2 <= 36 always (ii<=17)
      consume(g0 + 1, bufB);
    }
    consume(36, bufA);

    // z finish + dp partials
    {
      float part[16];
#pragma unroll
      for (int q = 0; q < 16; ++q) {
        const float z0 = ftanh(zacc[0][q] + b1v0);
        const float z1 = ftanh(zacc[1][q] + b1v1);
        part[q] = z0 * w2v0 + z1 * w2v1;
      }
#pragma unroll
      for (int m = 1; m <= 16; m <<= 1)
#pragma unroll
        for (int q = 0; q < 16; ++q) part[q] += __shfl_xor(part[q], m, 64);
      if (l31 == 0) {
#pragma unroll
        for (int q = 0; q < 16; ++q)
          partial[w][(q & 3) + ((q >> 2) << 3) + (half << 2)] = part[q];
      }
    }

    __syncthreads();  // B1: partial complete; all reads of hA/extA complete

    if (tid < MB) {
      float ssum = b2v;
#pragma unroll
      for (int ww = 0; ww < NWAVE; ++ww) ssum += partial[ww][tid];
      const float dpv = DPRv * ftanh(ssum);
      dp_lds[tid] = dpv;
      const size_t gb = ((size_t)(r0 + tid) * (Tn + 1) + t) * 2;
      const float g0 = gap[gb], g1 = gap[gb + 1];
      float* op = out + ((size_t)(r0 + tid) * (Tn + 1) + t) * 3;
      op[0] = g0; op[1] = g1; op[2] = dpv;
    }
    if (t < Tn - 1) {
      const int row = tid >> 4, kq = (tid & 15) << 2;
      const float4 v = *(const float4*)(noise + ((size_t)(r0 + row) * Tn + (t + 1)) * NZ + kq);
      ushort4 hb;
      hb.x = f2bf(v.x); hb.y = f2bf(v.y); hb.z = f2bf(v.z); hb.w = f2bf(v.w);
      *(ushort4*)((char*)extA + row * 256 + ((kq << 1) ^ ((row & 15) << 4))) = hb;
      if (tid < MB) {
        const size_t gb = ((size_t)(r0 + tid) * (Tn + 1) + (t + 1)) * 2;
        ushort4 hg;
        hg.x = f2bf(gap[gb]); hg.y = f2bf(gap[gb + 1]); hg.z = 0; hg.w = f2bf(clusf);
        *(ushort4*)((char*)extA + tid * 256 + (128 ^ ((tid & 15) << 4))) = hg;
      }
    }
    __syncthreads();  // B2: dp_lds visible; hA safe to overwrite

    if (t < Tn) {
      float dpv[16];
#pragma unroll
      for (int q = 0; q < 16; ++q)
        dpv[q] = dp_lds[(q & 3) + ((q >> 2) << 3) + (half << 2)];
#pragma unroll
      for (int s = 0; s < 2; ++s) {
        const int colb = (cb + s * 32 + l31) << 1;
#pragma unroll
        for (int q = 0; q < 16; ++q) {
          const float gi = acc[0][s][q] + biasv[0][s] + dpv[q] * wih2[0][s];
          const float gf = acc[1][s][q] + biasv[1][s] + dpv[q] * wih2[1][s];
          const float gg = acc[2][s][q] + biasv[2][s] + dpv[q] * wih2[2][s];
          const float go = acc[3][s][q] + biasv[3][s] + dpv[q] * wih2[3][s];
          float cv = (s == 0) ? c_reg0[q] : c_reg1[q];
          cv = fsig(gf) * cv + fsig(gi) * ftanh(gg);
          const float hv = fsig(go) * ftanh(cv);
          if (s == 0) c_reg0[q] = cv; else c_reg1[q] = cv;
          const int r = (q & 3) + ((q >> 2) << 3) + (half << 2);
          *(unsigned short*)((char*)hA + (r << 10) + (colb ^ (r << 4))) = f2bf(hv);
        }
      }
    }
    __syncthreads();  // B3: hA ready for next step
  }
}

extern "C" void kernel_launch(void* const* d_in, const int* in_sizes, int n_in,
                              void* d_out, int out_size, void* d_ws, size_t ws_size,
                              hipStream_t stream) {
  const float* noise   = (const float*)d_in[0];
  const float* cluster = (const float*)d_in[1];
  const float* gap     = (const float*)d_in[2];
  const float* Wih     = (const float*)d_in[3];
  const float* Whh     = (const float*)d_in[4];
  const float* bih     = (const float*)d_in[5];
  const float* bhh     = (const float*)d_in[6];
  const float* W1      = (const float*)d_in[7];
  const float* b1      = (const float*)d_in[8];
  const float* W2      = (const float*)d_in[9];
  const float* b2      = (const float*)d_in[10];

  unsigned short* us = (unsigned short*)d_ws;  // 1,515,520 shorts = 3.03 MB

  prep_pack<<<(STREAM_SHORTS / 8 + 255) / 256, 256, 0, stream>>>(Wih, Whh, W1, us);
  lstm_seq<<<NBLK, NTHREADS, 0, stream>>>(noise, cluster, gap, Wih, bih, bhh, b1, W2, b2,
                                          us, (float*)d_out);
}